// Round 1
// baseline (690.255 us; speedup 1.0000x reference)
//
#include <hip/hip_runtime.h>
#include <hip/hip_bf16.h>
#include <cstdint>
#include <cstddef>

typedef __attribute__((ext_vector_type(8))) short short8;
typedef __attribute__((ext_vector_type(4))) short short4v;
typedef __attribute__((ext_vector_type(4))) float float4v;
typedef __attribute__((ext_vector_type(4))) int int4v;

#define S_LEN 2048
#define NHEADS 16
#define DHEAD 128

__device__ __forceinline__ short f2bf(float f) {
    union { float f; unsigned u; } v; v.f = f;
    unsigned r = (v.u + 0x7fffu + ((v.u >> 16) & 1u)) >> 16;
    return (short)(r & 0xffffu);
}
// round-half-up bf16 pack: 2 VALU ops, error <= 1 ulp vs RNE
__device__ __forceinline__ short f2bf_rhu(float f) {
    union { float f; unsigned u; } v; v.f = f;
    return (short)((v.u + 0x8000u) >> 16);
}

typedef __attribute__((address_space(1))) void gvoid;
typedef __attribute__((address_space(3))) void lvoid;

__device__ __forceinline__ void gl_lds16(const void* g, void* l) {
    __builtin_amdgcn_global_load_lds((gvoid*)g, (lvoid*)l, 16, 0, 0);
}

__device__ __forceinline__ float4v mfma16(short8 a, short8 b, float4v c) {
    return __builtin_amdgcn_mfma_f32_16x16x32_bf16(a, b, c, 0, 0, 0);
}

// swizzled LDS tile addressing: tiles are arrays of 16B chunks.
__device__ __forceinline__ const char* lds8(const short* base, int row, int ch) {
    return (const char*)base + (((row << 3) + (ch ^ (row & 7))) << 4);
}
__device__ __forceinline__ const char* lds16a(const short* base, int row, int ch) {
    return (const char*)base + (((row << 4) + (ch ^ (row & 15))) << 4);
}

// ---------------- elementwise fp32 -> bf16 ----------------
__global__ __launch_bounds__(256)
void cvt_bf16(const float* __restrict__ X, short* __restrict__ Y) {
    size_t i = ((size_t)blockIdx.x * 256 + threadIdx.x) * 4;
    float4v v = *(const float4v*)(X + i);
    short4v o;
#pragma unroll
    for (int j = 0; j < 4; ++j) o[j] = f2bf(v[j]);
    *(short4v*)(Y + i) = o;
}

// ---------------- W[K][N] fp32 -> Wt[N][K] bf16, optional pre-scale ----------------
__global__ __launch_bounds__(256)
void tposew(const float* __restrict__ W, short* __restrict__ Wt, int K, int N, float scale) {
    __shared__ float t[32][33];
    int bx = blockIdx.x, by = blockIdx.y;
    int tx = threadIdx.x & 31, ty = threadIdx.x >> 5;
#pragma unroll
    for (int i = 0; i < 32; i += 8)
        t[ty + i][tx] = W[(size_t)(by * 32 + ty + i) * N + bx * 32 + tx];
    __syncthreads();
#pragma unroll
    for (int i = 0; i < 32; i += 8)
        Wt[(size_t)(bx * 32 + ty + i) * K + by * 32 + tx] = f2bf(t[tx][ty + i] * scale);
}

// ---------------- BT-GEMM: C[M][N] = A[M][K] * Bt[N][K]^T (bf16 in, f32 acc) ----
// MODE 0: store bf16 row-major; MODE 1: store f32 row-major;
// MODE 2: store bf16 scattered as Vt[b][n][s] (n = h*128+dh), i.e. ((b*2048+n)*2048 + s)
template <int MODE>
__global__ __launch_bounds__(256, 2)
void gemm_bt(const short* __restrict__ A, const short* __restrict__ Bt,
             void* __restrict__ Cv, int M, int N, int K) {
    __shared__ short sA[128 * 64];
    __shared__ short sB[128 * 64];
    const int tid = threadIdx.x;
    const int wid = tid >> 6, lane = tid & 63;
    const int quad = lane >> 4, l15 = lane & 15;
    const int n0 = blockIdx.x * 128, m0 = blockIdx.y * 128;
    const int wm = (wid & 1) * 64, wn = (wid >> 1) * 64;
    float4v acc[4][4] = {};
    for (int k0 = 0; k0 < K; k0 += 64) {
        __syncthreads();
#pragma unroll
        for (int i = 0; i < 4; ++i) {
            int c = i * 256 + tid;
            int row = c >> 3, kc = c & 7, g = kc ^ (row & 7);
            int lb = ((i << 8) + (wid << 6)) << 4;
            gl_lds16(A + (size_t)(m0 + row) * K + k0 + g * 8, (char*)(void*)sA + lb);
            gl_lds16(Bt + (size_t)(n0 + row) * K + k0 + g * 8, (char*)(void*)sB + lb);
        }
        __syncthreads();
#pragma unroll
        for (int ks = 0; ks < 2; ++ks) {
            short8 af[4], bf[4];
#pragma unroll
            for (int t = 0; t < 4; ++t) {
                int q = ks * 4 + quad;
                af[t] = *(const short8*)lds8(sA, wm + t * 16 + l15, q);
                bf[t] = *(const short8*)lds8(sB, wn + t * 16 + l15, q);
            }
#pragma unroll
            for (int mt = 0; mt < 4; ++mt)
#pragma unroll
                for (int nt = 0; nt < 4; ++nt)
                    acc[mt][nt] = mfma16(af[mt], bf[nt], acc[mt][nt]);
        }
    }
#pragma unroll
    for (int mt = 0; mt < 4; ++mt)
#pragma unroll
        for (int nt = 0; nt < 4; ++nt) {
            int rbase = m0 + wm + mt * 16 + quad * 4;
            int col = n0 + wn + nt * 16 + l15;
            if (MODE == 0) {
                short* Cb = (short*)Cv;
#pragma unroll
                for (int i = 0; i < 4; ++i)
                    Cb[(size_t)(rbase + i) * N + col] = f2bf(acc[mt][nt][i]);
            } else if (MODE == 1) {
                float* Cf = (float*)Cv;
#pragma unroll
                for (int i = 0; i < 4; ++i)
                    Cf[(size_t)(rbase + i) * N + col] = acc[mt][nt][i];
            } else {
                short4v pk;
#pragma unroll
                for (int i = 0; i < 4; ++i) pk[i] = f2bf(acc[mt][nt][i]);
                int bb = rbase >> 11, s = rbase & 2047;
                short* Cb = (short*)Cv;
                *(short4v*)(Cb + ((size_t)(bb * 2048 + col) * 2048 + s)) = pk;
            }
        }
}

// ---------------- fused differential attention (v4: T14 async-stage + setprio) ----
// Q pre-scaled by (1/sqrt(128))*log2(e) via Wq fold, so scores come out of the
// MFMA already in log2-domain: t = exp2(s) is the natural-exp of the scaled score.
// Pass 2 folds normalizers into exp args: t1/l1*log2e = exp2(s1 + c1).
// Staging is register-relayed (global->reg issued BEFORE the compute phase of the
// PREVIOUS tile's consumers; ds_write AFTER the loop-top barrier) so the
// __syncthreads vmcnt-drain only sees loads that had a full compute phase to land.
// Q,Kq: bf16 [4096][4096] (col = h*256 + split*128 + dh)
// Vt:   bf16 [B][NH][DH][S];  AO: f32 [4096][2048]
__global__ __launch_bounds__(256, 2)
void attn_kernel(const short* __restrict__ Q, const short* __restrict__ Kq,
                 const short* __restrict__ Vt, const float* __restrict__ lam,
                 float* __restrict__ AO) {
    __shared__ short sK1[64 * 128];   // 16 KB
    __shared__ short sK2[64 * 128];   // 16 KB
    __shared__ short sV[128 * 64];    // 16 KB
    __shared__ short sP[4][32 * 64];  // 16 KB (4 KB/wave)

    const int tid = threadIdx.x;
    const int wid = tid >> 6, lane = tid & 63;
    const int quad = lane >> 4, l15 = lane & 15;

    // XCD swizzle: 4 consecutive bh per XCD (assumes round-robin linear-id->XCD;
    // perf heuristic only, correctness-independent)
    const int xb = blockIdx.x;
    const int local = xb >> 3;
    const int bh = (xb & 7) * 4 + (local >> 4);
    const int qx = local & 15;
    const int b = bh >> 4, h = bh & 15;
    const int wrow = qx * 128 + wid * 32;

    const float lamh = lam[h];
    const float C0 = 0.5287663729448977f;  // log2(log2(e))

    short8 q1f[2][4], q2f[2][4];
    {
        const short* qb = Q + (size_t)(b * S_LEN + wrow) * 4096 + h * 256;
#pragma unroll
        for (int mt = 0; mt < 2; ++mt)
#pragma unroll
            for (int ks = 0; ks < 4; ++ks) {
                const short* p = qb + (size_t)(mt * 16 + l15) * 4096 + ks * 32 + quad * 8;
                q1f[mt][ks] = *(const short8*)p;
                q2f[mt][ks] = *(const short8*)(p + 128);
            }
    }
    const short* k1g = Kq + (size_t)(b * S_LEN) * 4096 + h * 256;
    const short* k2g = k1g + 128;
    const short* vg = Vt + (size_t)(b * NHEADS + h) * DHEAD * S_LEN;

    int offK[4], offV[4];
#pragma unroll
    for (int i = 0; i < 4; ++i) {
        int c = i * 256 + tid;
        int row = c >> 4, kc = c & 15;
        offK[i] = row * 4096 + ((kc ^ (row & 15)) << 3);
        int dh = c >> 3, vc = c & 7;
        offV[i] = dh * 2048 + ((vc ^ (dh & 7)) << 3);
    }
    // LDS dest for this thread's chunk i is byte (i*256+tid)*16 = i*4096 + tid*16
    char* dK1 = (char*)(void*)sK1 + (size_t)tid * 16;
    char* dK2 = (char*)(void*)sK2 + (size_t)tid * 16;
    char* dV = (char*)(void*)sV + (size_t)tid * 16;

    float l1a[2][4] = {}, l2a[2][4] = {};
    int4v kr1[4], kr2[4], vr[4];

    // ---- pass 1: l1 = sum exp2(s1), l2 = sum exp2(s2); no max needed (|s| small)
    // prologue: tile 0 -> regs
#pragma unroll
    for (int i = 0; i < 4; ++i) {
        kr1[i] = *(const int4v*)(k1g + offK[i]);
        kr2[i] = *(const int4v*)(k2g + offK[i]);
    }
    for (int kt = 0; kt < S_LEN; kt += 64) {
        __syncthreads();  // everyone done with previous tile; drains vmcnt (regs valid)
#pragma unroll
        for (int i = 0; i < 4; ++i) {
            *(int4v*)(dK1 + i * 4096) = kr1[i];
            *(int4v*)(dK2 + i * 4096) = kr2[i];
        }
        __syncthreads();  // tile visible
        if (kt + 64 < S_LEN) {  // issue next tile's loads; they fly during compute
            const short* k1b = k1g + (size_t)(kt + 64) * 4096;
            const short* k2b = k2g + (size_t)(kt + 64) * 4096;
#pragma unroll
            for (int i = 0; i < 4; ++i) {
                kr1[i] = *(const int4v*)(k1b + offK[i]);
                kr2[i] = *(const int4v*)(k2b + offK[i]);
            }
        }
#pragma unroll
        for (int nt = 0; nt < 4; ++nt) {
            float4v s1[2] = {}, s2[2] = {};
            int krow = nt * 16 + l15;
            __builtin_amdgcn_s_setprio(1);
#pragma unroll
            for (int ks = 0; ks < 4; ++ks) {
                int q = ks * 4 + quad;
                short8 kb1 = *(const short8*)lds16a(sK1, krow, q);
                short8 kb2 = *(const short8*)lds16a(sK2, krow, q);
#pragma unroll
                for (int mt = 0; mt < 2; ++mt) {
                    s1[mt] = mfma16(q1f[mt][ks], kb1, s1[mt]);
                    s2[mt] = mfma16(q2f[mt][ks], kb2, s2[mt]);
                }
            }
            __builtin_amdgcn_s_setprio(0);
#pragma unroll
            for (int mt = 0; mt < 2; ++mt)
#pragma unroll
                for (int r = 0; r < 4; ++r) {
                    l1a[mt][r] += __builtin_amdgcn_exp2f(s1[mt][r]);
                    l2a[mt][r] += __builtin_amdgcn_exp2f(s2[mt][r]);
                }
        }
    }

    // prologue for pass 2: tile 0 (K1,K2,V) -> regs; issued before the reduction
    // math below so the loads hide under it
#pragma unroll
    for (int i = 0; i < 4; ++i) {
        kr1[i] = *(const int4v*)(k1g + offK[i]);
        kr2[i] = *(const int4v*)(k2g + offK[i]);
        vr[i] = *(const int4v*)(vg + offV[i]);
    }

#pragma unroll
    for (int off = 1; off < 16; off <<= 1)
#pragma unroll
        for (int mt = 0; mt < 2; ++mt)
#pragma unroll
            for (int r = 0; r < 4; ++r) {
                l1a[mt][r] += __shfl_xor(l1a[mt][r], off, 64);
                l2a[mt][r] += __shfl_xor(l2a[mt][r], off, 64);
            }
    // fold normalizers into exp2 args: t1/l1*log2e = exp2(s1 + c1)
    const float llam = __log2f(lamh);
    float c1[2][4], c2[2][4];
#pragma unroll
    for (int mt = 0; mt < 2; ++mt)
#pragma unroll
        for (int r = 0; r < 4; ++r) {
            c1[mt][r] = C0 - __log2f(l1a[mt][r]);
            c2[mt][r] = C0 + llam - __log2f(l2a[mt][r]);
        }

    float lda[2][4] = {};
    float4v oacc[2][8] = {};

    // ---- pass 2: e = exp2(exp2(s1+c1) - exp2(s2+c2)); O += P@V
    for (int kt = 0; kt < S_LEN; kt += 64) {
        __syncthreads();  // everyone done reading previous sK/sV; regs valid
#pragma unroll
        for (int i = 0; i < 4; ++i) {
            *(int4v*)(dK1 + i * 4096) = kr1[i];
            *(int4v*)(dK2 + i * 4096) = kr2[i];
            *(int4v*)(dV + i * 4096) = vr[i];
        }
        __syncthreads();  // tile visible
        if (kt + 64 < S_LEN) {  // issue next tile's loads; they fly during compute
            const short* k1b = k1g + (size_t)(kt + 64) * 4096;
            const short* k2b = k2g + (size_t)(kt + 64) * 4096;
            const short* vb = vg + (kt + 64);
#pragma unroll
            for (int i = 0; i < 4; ++i) {
                kr1[i] = *(const int4v*)(k1b + offK[i]);
                kr2[i] = *(const int4v*)(k2b + offK[i]);
                vr[i] = *(const int4v*)(vb + offV[i]);
            }
        }
        short* sPw = sP[wid];
#pragma unroll
        for (int nt = 0; nt < 4; ++nt) {
            float4v s1[2] = {}, s2[2] = {};
            int krow = nt * 16 + l15;
            __builtin_amdgcn_s_setprio(1);
#pragma unroll
            for (int ks = 0; ks < 4; ++ks) {
                int q = ks * 4 + quad;
                short8 kb1 = *(const short8*)lds16a(sK1, krow, q);
                short8 kb2 = *(const short8*)lds16a(sK2, krow, q);
#pragma unroll
                for (int mt = 0; mt < 2; ++mt) {
                    s1[mt] = mfma16(q1f[mt][ks], kb1, s1[mt]);
                    s2[mt] = mfma16(q2f[mt][ks], kb2, s2[mt]);
                }
            }
            __builtin_amdgcn_s_setprio(0);
#pragma unroll
            for (int mt = 0; mt < 2; ++mt)
#pragma unroll
                for (int r = 0; r < 4; ++r) {
                    float u1 = __builtin_amdgcn_exp2f(s1[mt][r] + c1[mt][r]);
                    float u2 = __builtin_amdgcn_exp2f(s2[mt][r] + c2[mt][r]);
                    float e = __builtin_amdgcn_exp2f(u1 - u2);
                    lda[mt][r] += e;
                    int qrow = mt * 16 + quad * 4 + r;
                    int key = nt * 16 + l15;
                    *(short*)((char*)sPw +
                              ((((qrow << 3) + ((key >> 3) ^ (qrow & 7))) << 4) +
                               ((key & 7) << 1))) = f2bf_rhu(e);
                }
        }
        // PV: sP is wave-private (per-wave lgkm ordering suffices, no barrier);
        // sV protected by loop-top + post-store barriers
        __builtin_amdgcn_s_setprio(1);
#pragma unroll
        for (int kk = 0; kk < 2; ++kk) {
            short8 pa[2];
#pragma unroll
            for (int mt = 0; mt < 2; ++mt)
                pa[mt] = *(const short8*)lds8(sPw, mt * 16 + l15, kk * 4 + quad);
#pragma unroll
            for (int nt = 0; nt < 8; ++nt) {
                short8 vbf = *(const short8*)lds8(sV, nt * 16 + l15, kk * 4 + quad);
#pragma unroll
                for (int mt = 0; mt < 2; ++mt)
                    oacc[mt][nt] = mfma16(pa[mt], vbf, oacc[mt][nt]);
            }
        }
        __builtin_amdgcn_s_setprio(0);
    }
#pragma unroll
    for (int off = 1; off < 16; off <<= 1)
#pragma unroll
        for (int mt = 0; mt < 2; ++mt)
#pragma unroll
            for (int r = 0; r < 4; ++r)
                lda[mt][r] += __shfl_xor(lda[mt][r], off, 64);
#pragma unroll
    for (int mt = 0; mt < 2; ++mt) {
        float ild[4];
#pragma unroll
        for (int r = 0; r < 4; ++r) ild[r] = 1.0f / lda[mt][r];
#pragma unroll
        for (int nt = 0; nt < 8; ++nt)
#pragma unroll
            for (int r = 0; r < 4; ++r) {
                int row = b * S_LEN + wrow + mt * 16 + quad * 4 + r;
                int col = h * DHEAD + nt * 16 + l15;
                AO[(size_t)row * 2048 + col] = oacc[mt][nt][r] * ild[r];
            }
    }
}

// ---------------- RMS norm + scale * (1 - mean(lam)), f32 -> bf16 ----------------
__global__ __launch_bounds__(256)
void rms_kernel(const float* __restrict__ AO, const float* __restrict__ gs,
                const float* __restrict__ lam, short* __restrict__ Y) {
    int row = blockIdx.x, tid = threadIdx.x;
    const float* x = AO + (size_t)row * 2048;
    float4v v0 = *(const float4v*)(x + tid * 8);
    float4v v1 = *(const float4v*)(x + tid * 8 + 4);
    float ss = 0;
#pragma unroll
    for (int j = 0; j < 4; ++j) ss += v0[j] * v0[j] + v1[j] * v1[j];
#pragma unroll
    for (int off = 32; off > 0; off >>= 1) ss += __shfl_xor(ss, off, 64);
    __shared__ float wsum[4];
    if ((tid & 63) == 0) wsum[tid >> 6] = ss;
    __syncthreads();
    float tot = wsum[0] + wsum[1] + wsum[2] + wsum[3];
    float lm = 0;
#pragma unroll
    for (int i = 0; i < 16; ++i) lm += lam[i];
    float f = (1.0f - lm * (1.0f / 16.0f)) * rsqrtf(tot * (1.0f / 2048.0f) + 1e-6f);
    float4v g0 = *(const float4v*)(gs + tid * 8);
    float4v g1 = *(const float4v*)(gs + tid * 8 + 4);
    short4v o0, o1;
#pragma unroll
    for (int j = 0; j < 4; ++j) {
        o0[j] = f2bf(v0[j] * f * g0[j]);
        o1[j] = f2bf(v1[j] * f * g1[j]);
    }
    *(short4v*)(Y + (size_t)row * 2048 + tid * 8) = o0;
    *(short4v*)(Y + (size_t)row * 2048 + tid * 8 + 4) = o1;
}

extern "C" void kernel_launch(void* const* d_in, const int* in_sizes, int n_in,
                              void* d_out, int out_size, void* d_ws, size_t ws_size,
                              hipStream_t stream) {
    const float* x = (const float*)d_in[0];
    const float* Wq = (const float*)d_in[1];
    const float* Wk = (const float*)d_in[2];
    const float* Wv = (const float*)d_in[3];
    const float* Wo = (const float*)d_in[4];
    const float* nsc = (const float*)d_in[5];
    const float* lam = (const float*)d_in[6];
    float* out = (float*)d_out;
    (void)in_sizes; (void)n_in; (void)out_size; (void)ws_size;

    char* ws = (char*)d_ws;
    short* Xb  = (short*)(ws);                 // 16 MiB  [4096][2048]
    short* Wqt = (short*)(ws + 16777216);      // 16 MiB  [4096][2048]
    short* Wkt = (short*)(ws + 33554432);      // 16 MiB  [4096][2048]
    short* Wvt = (short*)(ws + 50331648);      //  8 MiB  [2048][2048]
    short* Wot = (short*)(ws + 58720256);      //  8 MiB  [2048][2048]
    short* Cq  = (short*)(ws + 67108864);      // 32 MiB  [4096][4096]
    short* Ck  = (short*)(ws + 100663296);     // 32 MiB  [4096][4096]
    short* Vt  = (short*)(ws + 134217728);     // 16 MiB  [2][16][128][2048]
    float* AO  = (float*)(ws + 16777216);      // 32 MiB, overlays Wqt+Wkt (dead by then)
    short* Nrm = (short*)(ws);                 // 16 MiB, overlays Xb (dead by then)

    // QKSCALE = (1/sqrt(128)) * log2(e), folded into Wq so scores exit the MFMA
    // in log2-domain
    const float QKSCALE = 0.12752965213246994f;

    cvt_bf16<<<8192, 256, 0, stream>>>(x, Xb);
    tposew<<<dim3(128, 64), 256, 0, stream>>>(Wq, Wqt, 2048, 4096, QKSCALE);
    tposew<<<dim3(128, 64), 256, 0, stream>>>(Wk, Wkt, 2048, 4096, 1.0f);
    tposew<<<dim3(64, 64), 256, 0, stream>>>(Wv, Wvt, 2048, 2048, 1.0f);
    tposew<<<dim3(64, 64), 256, 0, stream>>>(Wo, Wot, 2048, 2048, 1.0f);

    gemm_bt<0><<<dim3(32, 32), 256, 0, stream>>>(Xb, Wqt, (void*)Cq, 4096, 4096, 2048);
    gemm_bt<0><<<dim3(32, 32), 256, 0, stream>>>(Xb, Wkt, (void*)Ck, 4096, 4096, 2048);
    gemm_bt<2><<<dim3(16, 32), 256, 0, stream>>>(Xb, Wvt, (void*)Vt, 4096, 2048, 2048);

    attn_kernel<<<dim3(512), 256, 0, stream>>>(Cq, Ck, Vt, lam, AO);
    rms_kernel<<<4096, 256, 0, stream>>>(AO, nsc, lam, Nrm);
    gemm_bt<1><<<dim3(16, 32), 256, 0, stream>>>(Nrm, Wot, (void*)out, 4096, 2048, 2048);
}

// Round 3
// 602.348 us; speedup vs baseline: 1.1459x; 1.1459x over previous
//
#include <hip/hip_runtime.h>
#include <hip/hip_bf16.h>
#include <cstdint>
#include <cstddef>

typedef __attribute__((ext_vector_type(8))) short short8;
typedef __attribute__((ext_vector_type(4))) short short4v;
typedef __attribute__((ext_vector_type(4))) float float4v;

#define S_LEN 2048
#define NHEADS 16
#define DHEAD 128

__device__ __forceinline__ short f2bf(float f) {
    union { float f; unsigned u; } v; v.f = f;
    unsigned r = (v.u + 0x7fffu + ((v.u >> 16) & 1u)) >> 16;
    return (short)(r & 0xffffu);
}
// round-half-up bf16 pack: 2 VALU ops, error <= 1 ulp vs RNE
__device__ __forceinline__ short f2bf_rhu(float f) {
    union { float f; unsigned u; } v; v.f = f;
    return (short)((v.u + 0x8000u) >> 16);
}

typedef __attribute__((address_space(1))) void gvoid;
typedef __attribute__((address_space(3))) void lvoid;

__device__ __forceinline__ void gl_lds16(const void* g, void* l) {
    __builtin_amdgcn_global_load_lds((gvoid*)g, (lvoid*)l, 16, 0, 0);
}

__device__ __forceinline__ float4v mfma16(short8 a, short8 b, float4v c) {
    return __builtin_amdgcn_mfma_f32_16x16x32_bf16(a, b, c, 0, 0, 0);
}

// swizzled LDS tile addressing: tiles are arrays of 16B chunks.
// lds8: 8-chunk rows (128 bf16), swizzle over 8 chunks
__device__ __forceinline__ const char* lds8(const short* base, int row, int ch) {
    return (const char*)base + (((row << 3) + (ch ^ (row & 7))) << 4);
}
// lds16a: 16-chunk rows (128 bf16 cols stored as 16 chunks), swizzle over 16
__device__ __forceinline__ const char* lds16a(const short* base, int row, int ch) {
    return (const char*)base + (((row << 4) + (ch ^ (row & 15))) << 4);
}
// lds4: 4-chunk rows (32 bf16), swizzle uses (row>>1)&3 so 16 consecutive rows
// hit 8 distinct bank groups (2-way = free); (row&3) would give 4-way.
__device__ __forceinline__ const char* lds4(const short* base, int row, int ch) {
    return (const char*)base + (((row << 2) + (ch ^ ((row >> 1) & 3))) << 4);
}

// ---------------- elementwise fp32 -> bf16 ----------------
__global__ __launch_bounds__(256)
void cvt_bf16(const float* __restrict__ X, short* __restrict__ Y) {
    size_t i = ((size_t)blockIdx.x * 256 + threadIdx.x) * 4;
    float4v v = *(const float4v*)(X + i);
    short4v o;
#pragma unroll
    for (int j = 0; j < 4; ++j) o[j] = f2bf(v[j]);
    *(short4v*)(Y + i) = o;
}

// ---------------- W[K][N] fp32 -> Wt[N][K] bf16, optional pre-scale ----------------
__global__ __launch_bounds__(256)
void tposew(const float* __restrict__ W, short* __restrict__ Wt, int K, int N, float scale) {
    __shared__ float t[32][33];
    int bx = blockIdx.x, by = blockIdx.y;
    int tx = threadIdx.x & 31, ty = threadIdx.x >> 5;
#pragma unroll
    for (int i = 0; i < 32; i += 8)
        t[ty + i][tx] = W[(size_t)(by * 32 + ty + i) * N + bx * 32 + tx];
    __syncthreads();
#pragma unroll
    for (int i = 0; i < 32; i += 8)
        Wt[(size_t)(bx * 32 + ty + i) * K + by * 32 + tx] = f2bf(t[tx][ty + i] * scale);
}

// ---------------- BT-GEMM: C[M][N] = A[M][K] * Bt[N][K]^T (bf16 in, f32 acc) ----
// Double-buffered LDS, ONE __syncthreads per K-step placed BEFORE the issue:
// at the barrier the only outstanding loads are tile t's (issued one full
// compute phase ago), so the compiler's conservative vmcnt(0) drain is cheap.
// WAR on buf^1 is safe: it was last read in iteration t-1, behind the barrier.
// MODE 0: store bf16 row-major; MODE 1: store f32 row-major;
// MODE 2: store bf16 scattered as Vt[b][n][s] (n = h*128+dh), i.e. ((b*2048+n)*2048 + s)
template <int MODE>
__global__ __launch_bounds__(256, 2)
void gemm_bt(const short* __restrict__ A, const short* __restrict__ Bt,
             void* __restrict__ Cv, int M, int N, int K) {
    __shared__ short sA[2][128 * 64];
    __shared__ short sB[2][128 * 64];
    const int tid = threadIdx.x;
    const int wid = tid >> 6, lane = tid & 63;
    const int quad = lane >> 4, l15 = lane & 15;
    const int n0 = blockIdx.x * 128, m0 = blockIdx.y * 128;
    const int wm = (wid & 1) * 64, wn = (wid >> 1) * 64;

    size_t aoff[4], boff[4];
    int lb[4];
#pragma unroll
    for (int i = 0; i < 4; ++i) {
        int c = i * 256 + tid;
        int row = c >> 3, kc = c & 7, g = kc ^ (row & 7);
        aoff[i] = (size_t)(m0 + row) * K + g * 8;
        boff[i] = (size_t)(n0 + row) * K + g * 8;
        lb[i] = ((i << 8) + (wid << 6)) << 4;
    }

    float4v acc[4][4] = {};
    // prologue: issue K-tile 0 into buf 0
#pragma unroll
    for (int i = 0; i < 4; ++i) {
        gl_lds16(A + aoff[i], (char*)(void*)sA[0] + lb[i]);
        gl_lds16(Bt + boff[i], (char*)(void*)sB[0] + lb[i]);
    }
    const int NK = K >> 6;
    for (int t = 0; t < NK; ++t) {
        __syncthreads();  // drains tile t's loads (they flew under tile t-1's compute)
        if (t + 1 < NK) {
            int k0 = (t + 1) << 6;
            char* dA = (char*)(void*)sA[(t + 1) & 1];
            char* dB = (char*)(void*)sB[(t + 1) & 1];
#pragma unroll
            for (int i = 0; i < 4; ++i) {
                gl_lds16(A + aoff[i] + k0, dA + lb[i]);
                gl_lds16(Bt + boff[i] + k0, dB + lb[i]);
            }
        }
        const short* a = sA[t & 1];
        const short* b = sB[t & 1];
#pragma unroll
        for (int ks = 0; ks < 2; ++ks) {
            short8 af[4], bf[4];
#pragma unroll
            for (int tt = 0; tt < 4; ++tt) {
                int q = ks * 4 + quad;
                af[tt] = *(const short8*)lds8(a, wm + tt * 16 + l15, q);
                bf[tt] = *(const short8*)lds8(b, wn + tt * 16 + l15, q);
            }
#pragma unroll
            for (int mt = 0; mt < 4; ++mt)
#pragma unroll
                for (int nt = 0; nt < 4; ++nt)
                    acc[mt][nt] = mfma16(af[mt], bf[nt], acc[mt][nt]);
        }
    }
#pragma unroll
    for (int mt = 0; mt < 4; ++mt)
#pragma unroll
        for (int nt = 0; nt < 4; ++nt) {
            int rbase = m0 + wm + mt * 16 + quad * 4;
            int col = n0 + wn + nt * 16 + l15;
            if (MODE == 0) {
                short* Cb = (short*)Cv;
#pragma unroll
                for (int i = 0; i < 4; ++i)
                    Cb[(size_t)(rbase + i) * N + col] = f2bf(acc[mt][nt][i]);
            } else if (MODE == 1) {
                float* Cf = (float*)Cv;
#pragma unroll
                for (int i = 0; i < 4; ++i)
                    Cf[(size_t)(rbase + i) * N + col] = acc[mt][nt][i];
            } else {
                short4v pk;
#pragma unroll
                for (int i = 0; i < 4; ++i) pk[i] = f2bf(acc[mt][nt][i]);
                int bb = rbase >> 11, s = rbase & 2047;
                short* Cb = (short*)Cv;
                *(short4v*)(Cb + ((size_t)(bb * 2048 + col) * 2048 + s)) = pk;
            }
        }
}

// ---------------- fused differential attention (v6: dbuf + single-barrier overlap) --
// Q pre-scaled by (1/sqrt(128))*log2(e) via Wq fold, so scores come out of the
// MFMA already in log2-domain: t = exp2(s) is the natural-exp of the scaled score.
// Pass 2 folds normalizers into exp args: t1/l1*log2e = exp2(s1 + c1).
// Staging: global_load_lds (zero VGPR cost) into DOUBLE-buffered KVBLK=32 tiles.
// One __syncthreads per tile, placed BEFORE the issue: at barrier-top the only
// outstanding loads are tile it's, issued one full compute phase earlier — the
// compiler's vmcnt(0) drain is then cheap. No raw barriers, no asm waitcnt.
// LDS = 56 KB -> 2 blocks/CU.
// Q,Kq: bf16 [4096][4096] (col = h*256 + split*128 + dh)
// Vt:   bf16 [B][NH][DH][S];  AO: f32 [4096][2048]
__global__ __launch_bounds__(256, 2)
void attn_kernel(const short* __restrict__ Q, const short* __restrict__ Kq,
                 const short* __restrict__ Vt, const float* __restrict__ lam,
                 float* __restrict__ AO) {
    __shared__ short sK1[2][32 * 128];  // 2 x 8 KB
    __shared__ short sK2[2][32 * 128];  // 2 x 8 KB
    __shared__ short sV[2][128 * 32];   // 2 x 8 KB
    __shared__ short sP[4][32 * 32];    // 8 KB (2 KB/wave)

    const int tid = threadIdx.x;
    const int wid = tid >> 6, lane = tid & 63;
    const int quad = lane >> 4, l15 = lane & 15;

    // XCD swizzle: 4 consecutive bh per XCD (assumes round-robin linear-id->XCD;
    // perf heuristic only, correctness-independent)
    const int xb = blockIdx.x;
    const int local = xb >> 3;
    const int bh = (xb & 7) * 4 + (local >> 4);
    const int qx = local & 15;
    const int b = bh >> 4, h = bh & 15;
    const int wrow = qx * 128 + wid * 32;

    const float lamh = lam[h];
    const float C0 = 0.5287663729448977f;  // log2(log2(e))

    short8 q1f[2][4], q2f[2][4];
    {
        const short* qb = Q + (size_t)(b * S_LEN + wrow) * 4096 + h * 256;
#pragma unroll
        for (int mt = 0; mt < 2; ++mt)
#pragma unroll
            for (int ks = 0; ks < 4; ++ks) {
                const short* p = qb + (size_t)(mt * 16 + l15) * 4096 + ks * 32 + quad * 8;
                q1f[mt][ks] = *(const short8*)p;
                q2f[mt][ks] = *(const short8*)(p + 128);
            }
    }
    const short* k1g = Kq + (size_t)(b * S_LEN) * 4096 + h * 256;
    const short* k2g = k1g + 128;
    const short* vg = Vt + (size_t)(b * NHEADS + h) * DHEAD * S_LEN;

    // K tile: 32 rows x 128 cols = 512 16B-chunks; chunk c=(i*256+tid):
    //   row=c>>4, col-chunk kc=c&15, global source chunk g = kc ^ (row&15)
    // V tile: 128 rows x 32 cols = 512 chunks; row dh=c>>2, vc=c&3,
    //   source chunk g = vc ^ ((dh>>1)&3)  (matches lds4 read swizzle)
    int offK[2], offV[2], lbs[2];
#pragma unroll
    for (int i = 0; i < 2; ++i) {
        int c = i * 256 + tid;
        int row = c >> 4, kc = c & 15;
        offK[i] = row * 4096 + ((kc ^ (row & 15)) << 3);
        int dh = c >> 2, vc = c & 3;
        offV[i] = dh * 2048 + ((vc ^ ((dh >> 1) & 3)) << 3);
        lbs[i] = ((i << 8) + (wid << 6)) << 4;  // wave-uniform LDS base (chunk i*256+wid*64)
    }

    float l1a[2][4] = {}, l2a[2][4] = {};

    const int NT = S_LEN / 32;  // 64 tiles

    // ---- pass 1: l1 = sum exp2(s1), l2 = sum exp2(s2); no max needed (|s| small)
    // prologue: issue tile 0 into buf 0
#pragma unroll
    for (int i = 0; i < 2; ++i) {
        gl_lds16(k1g + offK[i], (char*)(void*)sK1[0] + lbs[i]);
        gl_lds16(k2g + offK[i], (char*)(void*)sK2[0] + lbs[i]);
    }
    for (int it = 0; it < NT; ++it) {
        __syncthreads();  // drains tile it's loads (flew under tile it-1's compute)
        if (it + 1 < NT) {
            const short* k1b = k1g + (size_t)(it + 1) * 32 * 4096;
            const short* k2b = k2g + (size_t)(it + 1) * 32 * 4096;
            char* dK1 = (char*)(void*)sK1[(it + 1) & 1];
            char* dK2 = (char*)(void*)sK2[(it + 1) & 1];
#pragma unroll
            for (int i = 0; i < 2; ++i) {
                gl_lds16(k1b + offK[i], dK1 + lbs[i]);
                gl_lds16(k2b + offK[i], dK2 + lbs[i]);
            }
        }
        const short* k1 = sK1[it & 1];
        const short* k2 = sK2[it & 1];
#pragma unroll
        for (int nt = 0; nt < 2; ++nt) {
            float4v s1[2] = {}, s2[2] = {};
            int krow = nt * 16 + l15;
            __builtin_amdgcn_s_setprio(1);
#pragma unroll
            for (int ks = 0; ks < 4; ++ks) {
                int q = ks * 4 + quad;
                short8 kb1 = *(const short8*)lds16a(k1, krow, q);
                short8 kb2 = *(const short8*)lds16a(k2, krow, q);
#pragma unroll
                for (int mt = 0; mt < 2; ++mt) {
                    s1[mt] = mfma16(q1f[mt][ks], kb1, s1[mt]);
                    s2[mt] = mfma16(q2f[mt][ks], kb2, s2[mt]);
                }
            }
            __builtin_amdgcn_s_setprio(0);
#pragma unroll
            for (int mt = 0; mt < 2; ++mt)
#pragma unroll
                for (int r = 0; r < 4; ++r) {
                    l1a[mt][r] += __builtin_amdgcn_exp2f(s1[mt][r]);
                    l2a[mt][r] += __builtin_amdgcn_exp2f(s2[mt][r]);
                }
        }
    }

    // prologue for pass 2: issue tile 0 (K1,K2,V) into buf 0; loads fly under the
    // reduction math below. Buf 0 was last read in pass-1 iteration NT-2, and all
    // waves are past the barrier at top of NT-1, so the write is WAR-safe.
#pragma unroll
    for (int i = 0; i < 2; ++i) {
        gl_lds16(k1g + offK[i], (char*)(void*)sK1[0] + lbs[i]);
        gl_lds16(k2g + offK[i], (char*)(void*)sK2[0] + lbs[i]);
        gl_lds16(vg + offV[i], (char*)(void*)sV[0] + lbs[i]);
    }

#pragma unroll
    for (int off = 1; off < 16; off <<= 1)
#pragma unroll
        for (int mt = 0; mt < 2; ++mt)
#pragma unroll
            for (int r = 0; r < 4; ++r) {
                l1a[mt][r] += __shfl_xor(l1a[mt][r], off, 64);
                l2a[mt][r] += __shfl_xor(l2a[mt][r], off, 64);
            }
    // fold normalizers into exp2 args: t1/l1*log2e = exp2(s1 + c1)
    const float llam = __log2f(lamh);
    float c1[2][4], c2[2][4];
#pragma unroll
    for (int mt = 0; mt < 2; ++mt)
#pragma unroll
        for (int r = 0; r < 4; ++r) {
            c1[mt][r] = C0 - __log2f(l1a[mt][r]);
            c2[mt][r] = C0 + llam - __log2f(l2a[mt][r]);
        }

    float lda[2][4] = {};
    float4v oacc[2][8] = {};

    // ---- pass 2: e = exp2(exp2(s1+c1) - exp2(s2+c2)); O += P@V
    for (int it = 0; it < NT; ++it) {
        __syncthreads();  // drains tile it's loads
        if (it + 1 < NT) {
            const short* k1b = k1g + (size_t)(it + 1) * 32 * 4096;
            const short* k2b = k2g + (size_t)(it + 1) * 32 * 4096;
            const short* vb = vg + (it + 1) * 32;
            char* dK1 = (char*)(void*)sK1[(it + 1) & 1];
            char* dK2 = (char*)(void*)sK2[(it + 1) & 1];
            char* dV = (char*)(void*)sV[(it + 1) & 1];
#pragma unroll
            for (int i = 0; i < 2; ++i) {
                gl_lds16(k1b + offK[i], dK1 + lbs[i]);
                gl_lds16(k2b + offK[i], dK2 + lbs[i]);
                gl_lds16(vb + offV[i], dV + lbs[i]);
            }
        }
        const short* k1 = sK1[it & 1];
        const short* k2 = sK2[it & 1];
        const short* v = sV[it & 1];
        short* sPw = sP[wid];
#pragma unroll
        for (int nt = 0; nt < 2; ++nt) {
            float4v s1[2] = {}, s2[2] = {};
            int krow = nt * 16 + l15;
            __builtin_amdgcn_s_setprio(1);
#pragma unroll
            for (int ks = 0; ks < 4; ++ks) {
                int q = ks * 4 + quad;
                short8 kb1 = *(const short8*)lds16a(k1, krow, q);
                short8 kb2 = *(const short8*)lds16a(k2, krow, q);
#pragma unroll
                for (int mt = 0; mt < 2; ++mt) {
                    s1[mt] = mfma16(q1f[mt][ks], kb1, s1[mt]);
                    s2[mt] = mfma16(q2f[mt][ks], kb2, s2[mt]);
                }
            }
            __builtin_amdgcn_s_setprio(0);
#pragma unroll
            for (int mt = 0; mt < 2; ++mt)
#pragma unroll
                for (int r = 0; r < 4; ++r) {
                    float u1 = __builtin_amdgcn_exp2f(s1[mt][r] + c1[mt][r]);
                    float u2 = __builtin_amdgcn_exp2f(s2[mt][r] + c2[mt][r]);
                    float e = __builtin_amdgcn_exp2f(u1 - u2);
                    lda[mt][r] += e;
                    int qrow = mt * 16 + quad * 4 + r;
                    int key = nt * 16 + l15;
                    *(short*)((char*)sPw +
                              ((((qrow << 2) + ((key >> 3) ^ ((qrow >> 1) & 3))) << 4) +
                               ((key & 7) << 1))) = f2bf_rhu(e);
                }
        }
        // PV: sP is wave-private (per-wave lgkm ordering suffices, no barrier);
        // sV[it&1] protected by the barrier at the top of this iteration
        __builtin_amdgcn_s_setprio(1);
        {
            short8 pa[2];
#pragma unroll
            for (int mt = 0; mt < 2; ++mt)
                pa[mt] = *(const short8*)lds4(sPw, mt * 16 + l15, quad);
#pragma unroll
            for (int nt = 0; nt < 8; ++nt) {
                short8 vbf = *(const short8*)lds4(v, nt * 16 + l15, quad);
#pragma unroll
                for (int mt = 0; mt < 2; ++mt)
                    oacc[mt][nt] = mfma16(pa[mt], vbf, oacc[mt][nt]);
            }
        }
        __builtin_amdgcn_s_setprio(0);
    }
#pragma unroll
    for (int off = 1; off < 16; off <<= 1)
#pragma unroll
        for (int mt = 0; mt < 2; ++mt)
#pragma unroll
            for (int r = 0; r < 4; ++r)
                lda[mt][r] += __shfl_xor(lda[mt][r], off, 64);
#pragma unroll
    for (int mt = 0; mt < 2; ++mt) {
        float ild[4];
#pragma unroll
        for (int r = 0; r < 4; ++r) ild[r] = 1.0f / lda[mt][r];
#pragma unroll
        for (int nt = 0; nt < 8; ++nt)
#pragma unroll
            for (int r = 0; r < 4; ++r) {
                int row = b * S_LEN + wrow + mt * 16 + quad * 4 + r;
                int col = h * DHEAD + nt * 16 + l15;
                AO[(size_t)row * 2048 + col] = oacc[mt][nt][r] * ild[r];
            }
    }
}

// ---------------- RMS norm + scale * (1 - mean(lam)), f32 -> bf16 ----------------
__global__ __launch_bounds__(256)
void rms_kernel(const float* __restrict__ AO, const float* __restrict__ gs,
                const float* __restrict__ lam, short* __restrict__ Y) {
    int row = blockIdx.x, tid = threadIdx.x;
    const float* x = AO + (size_t)row * 2048;
    float4v v0 = *(const float4v*)(x + tid * 8);
    float4v v1 = *(const float4v*)(x + tid * 8 + 4);
    float ss = 0;
#pragma unroll
    for (int j = 0; j < 4; ++j) ss += v0[j] * v0[j] + v1[j] * v1[j];
#pragma unroll
    for (int off = 32; off > 0; off >>= 1) ss += __shfl_xor(ss, off, 64);
    __shared__ float wsum[4];
    if ((tid & 63) == 0) wsum[tid >> 6] = ss;
    __syncthreads();
    float tot = wsum[0] + wsum[1] + wsum[2] + wsum[3];
    float lm = 0;
#pragma unroll
    for (int i = 0; i < 16; ++i) lm += lam[i];
    float f = (1.0f - lm * (1.0f / 16.0f)) * rsqrtf(tot * (1.0f / 2048.0f) + 1e-6f);
    float4v g0 = *(const float4v*)(gs + tid * 8);
    float4v g1 = *(const float4v*)(gs + tid * 8 + 4);
    short4v o0, o1;
#pragma unroll
    for (int j = 0; j < 4; ++j) {
        o0[j] = f2bf(v0[j] * f * g0[j]);
        o1[j] = f2bf(v1[j] * f * g1[j]);
    }
    *(short4v*)(Y + (size_t)row * 2048 + tid * 8) = o0;
    *(short4v*)(Y + (size_t)row * 2048 + tid * 8 + 4) = o1;
}

extern "C" void kernel_launch(void* const* d_in, const int* in_sizes, int n_in,
                              void* d_out, int out_size, void* d_ws, size_t ws_size,
                              hipStream_t stream) {
    const float* x = (const float*)d_in[0];
    const float* Wq = (const float*)d_in[1];
    const float* Wk = (const float*)d_in[2];
    const float* Wv = (const float*)d_in[3];
    const float* Wo = (const float*)d_in[4];
    const float* nsc = (const float*)d_in[5];
    const float* lam = (const float*)d_in[6];
    float* out = (float*)d_out;
    (void)in_sizes; (void)n_in; (void)out_size; (void)ws_size;

    char* ws = (char*)d_ws;
    short* Xb  = (short*)(ws);                 // 16 MiB  [4096][2048]
    short* Wqt = (short*)(ws + 16777216);      // 16 MiB  [4096][2048]
    short* Wkt = (short*)(ws + 33554432);      // 16 MiB  [4096][2048]
    short* Wvt = (short*)(ws + 50331648);      //  8 MiB  [2048][2048]
    short* Wot = (short*)(ws + 58720256);      //  8 MiB  [2048][2048]
    short* Cq  = (short*)(ws + 67108864);      // 32 MiB  [4096][4096]
    short* Ck  = (short*)(ws + 100663296);     // 32 MiB  [4096][4096]
    short* Vt  = (short*)(ws + 134217728);     // 16 MiB  [2][16][128][2048]
    float* AO  = (float*)(ws + 16777216);      // 32 MiB, overlays Wqt+Wkt (dead by then)
    short* Nrm = (short*)(ws);                 // 16 MiB, overlays Xb (dead by then)

    // QKSCALE = (1/sqrt(128)) * log2(e), folded into Wq so scores exit the MFMA
    // in log2-domain
    const float QKSCALE = 0.12752965213246994f;

    cvt_bf16<<<8192, 256, 0, stream>>>(x, Xb);
    tposew<<<dim3(128, 64), 256, 0, stream>>>(Wq, Wqt, 2048, 4096, QKSCALE);
    tposew<<<dim3(128, 64), 256, 0, stream>>>(Wk, Wkt, 2048, 4096, 1.0f);
    tposew<<<dim3(64, 64), 256, 0, stream>>>(Wv, Wvt, 2048, 2048, 1.0f);
    tposew<<<dim3(64, 64), 256, 0, stream>>>(Wo, Wot, 2048, 2048, 1.0f);

    gemm_bt<0><<<dim3(32, 32), 256, 0, stream>>>(Xb, Wqt, (void*)Cq, 4096, 4096, 2048);
    gemm_bt<0><<<dim3(32, 32), 256, 0, stream>>>(Xb, Wkt, (void*)Ck, 4096, 4096, 2048);
    gemm_bt<2><<<dim3(16, 32), 256, 0, stream>>>(Xb, Wvt, (void*)Vt, 4096, 2048, 2048);

    attn_kernel<<<dim3(512), 256, 0, stream>>>(Cq, Ck, Vt, lam, AO);
    rms_kernel<<<4096, 256, 0, stream>>>(AO, nsc, lam, Nrm);
    gemm_bt<1><<<dim3(16, 32), 256, 0, stream>>>(Nrm, Wot, (void*)out, 4096, 2048, 2048);
}